// Round 11
// baseline (161.994 us; speedup 1.0000x reference)
//
#include <hip/hip_runtime.h>
#include <cstdint>

// DetNet NMS, round 11 (round-10 producer/consumer design, DEADLOCK FIXED).
// Round-10 bug: h_prog[hh] only advanced after the helper's NEXT owned chunk
// completed, which can require res_prog > T+3 while the resolver waits on
// h_prog — circular wait => hang. Fix: h_prog[hh] = smallest owned chunk not
// yet applied (init hh; after applying owned chunk c publish c+7; INT_MAX at
// end). Resolver spin (any hp < T-2) == "some chunk <= T-3 unapplied", now
// satisfiable without the helper starting future chunks. Liveness: helper
// owning c <= T-3 only needs res_prog > c, already published.
//
//   wave 0  (resolver): serial chain only — spin-check, LDS dead-pair read,
//       ctz+readlane resolve, publish keptmask+progress. Depth-3 WSlot
//       prefetch, NO row slots -> no spills.
//   waves 1-7 (helpers): chunk c == (wv-1) mod 7; after res_prog > c, load
//       kept rows (4-slot dummy-padded batches) and atomicOr into the shared
//       LDS dead-vector; publish h_prog.
// Correctness: resolver at T spins until all chunks <= T-3 applied; T-1/T-2
// keeps covered by register carries (n1/n2 readlanes); concurrent helper
// writes for T-1/T-2 are OR-idempotent double-cover; garbage words of kept
// rows only land in dead words already consumed. sdead init encodes V.
//
//   K2 (256 blocks): ballot-compact valid keys, V^2 rank scan (unchanged).
//   K_MASK (256x8):  suppression-bit matrix (unchanged).
//
// All decision-critical FP math uses __f*_rn in exact ref op order (absmax
// 0.0 in rounds 1-4, 6-9).

#define M_TOT 8192
#define NMS_T 0.3f

// ws layout (bytes)
#define WS_BOX   65536      // float4[8192]
#define WS_D     196608     // float[40960]
#define WS_VCNT  360448     // u32
#define WS_ZROW  393216     // u64[128] dummy zero row (zeroed by k2)
#define WS_MASK  524288     // u64[8192*128] = 8 MB

typedef unsigned long long u64t;

__device__ __forceinline__ uint32_t desc_key(float sv) {
    uint32_t u = __float_as_uint(sv);
    uint32_t m = (u & 0x80000000u) ? ~u : (u | 0x80000000u); // asc monotone
    return ~m;                                               // desc
}

// wave-uniform-index 64-bit broadcast via v_readlane (VALU latency)
__device__ __forceinline__ u64t rdl64(u64t v, int sl) {
    unsigned lo = (unsigned)__builtin_amdgcn_readlane((int)(unsigned)v, sl);
    unsigned hi = (unsigned)__builtin_amdgcn_readlane((int)(unsigned)(v >> 32), sl);
    return ((u64t)hi << 32) | lo;
}

__device__ __forceinline__ int scatter_one(
    int i, int rank, u64t key,
    const float* __restrict__ det, const float* __restrict__ offsets,
    const float* __restrict__ scales,
    float4* __restrict__ boxes_srt, float* __restrict__ d_srt)
{
    uint32_t dkey = (uint32_t)(key >> 16);
    if (dkey >= 0x7FFFFFFFu) return 0;   // score <= 0: row stays zero
    int g = i >> 10;
    float d0 = __fadd_rn(offsets[g*5+0], __fmul_rn(det[i*5+0], scales[g*5+0]));
    float d1 = __fadd_rn(offsets[g*5+1], __fmul_rn(det[i*5+1], scales[g*5+1]));
    float d2 = __fadd_rn(offsets[g*5+2], __fmul_rn(det[i*5+2], scales[g*5+2]));
    float d3 = __fadd_rn(offsets[g*5+3], __fmul_rn(det[i*5+3], scales[g*5+3]));
    float d4 = __fadd_rn(offsets[g*5+4], __fmul_rn(det[i*5+4], scales[g*5+4]));
    d_srt[rank*5+0] = d0; d_srt[rank*5+1] = d1; d_srt[rank*5+2] = d2;
    d_srt[rank*5+3] = d3; d_srt[rank*5+4] = d4;
    float hw = __fmul_rn(d3, 0.5f), hh = __fmul_rn(d4, 0.5f);
    boxes_srt[rank] = make_float4(__fsub_rn(d1, hw), __fsub_rn(d2, hh),
                                  __fadd_rn(d1, hw), __fadd_rn(d2, hh));
    return 1;
}

__global__ __launch_bounds__(256) void k2_rank(
    const float* __restrict__ det, const float* __restrict__ offsets,
    const float* __restrict__ scales, const float* __restrict__ bounds,
    float4* __restrict__ boxes_srt, float* __restrict__ d_srt,
    unsigned int* __restrict__ vcnt, u64t* __restrict__ zrow,
    float* __restrict__ out)
{
    __shared__ u64t skey[M_TOT];
    __shared__ float soff[40], sscl[40], sbnd[32];
    __shared__ int sTop;
    int t = threadIdx.x;
    int lane = t & 63;
    if (t == 0) sTop = 0;
    if (t < 40) { soff[t] = offsets[t]; sscl[t] = scales[t]; }
    if (t < 32) { sbnd[t] = bounds[t]; }
    if (blockIdx.x == 0 && t < 128) zrow[t] = 0ull;
    __syncthreads();

    #pragma unroll 4
    for (int s = 0; s < 32; ++s) {
        int u = s * 256 + t;
        int g = u >> 10;
        float raw_s = det[u * 5 + 0];
        float cx    = det[u * 5 + 1];
        float cy    = det[u * 5 + 2];
        float score = __fadd_rn(soff[g * 5 + 0], __fmul_rn(raw_s, sscl[g * 5 + 0]));
        bool valid = (cx < sbnd[g*4+1]) && (cx > sbnd[g*4+0]) &&
                     (cy < sbnd[g*4+3]) && (cy > sbnd[g*4+2]);
        float sv = valid ? score : -1.0f;
        uint32_t dk = desc_key(sv);
        bool push = dk < 0x7FFFFFFFu;
        u64t key = ((u64t)dk << 16) | (unsigned)u;
        u64t bal = __ballot(push);
        if (bal) {
            int lw = 0;
            if (lane == 0) lw = atomicAdd(&sTop, __popcll(bal));
            int wbase = __builtin_amdgcn_readfirstlane(lw);
            if (push) {
                int off = __popcll(bal & ((1ull << lane) - 1ull));
                skey[wbase + off] = key;
            }
        }
    }
    __syncthreads();
    int V = sTop;
    int Vpad = (V + 15) & ~15;
    if (t < Vpad - V) skey[V + t] = ~0ull;
    {
        int zb = blockIdx.x * 160;
        for (int z = zb + t; z < zb + 160; z += 256) out[z] = 0.0f;
    }
    __syncthreads();
    if (t == 0) *vcnt = (unsigned)V;

    int grp = t >> 3;
    int jq  = t & 7;
    int i = blockIdx.x * 32 + grp;
    int g = i >> 10;
    float raw_s = det[i * 5 + 0];
    float cx    = det[i * 5 + 1];
    float cy    = det[i * 5 + 2];
    float score = __fadd_rn(soff[g * 5 + 0], __fmul_rn(raw_s, sscl[g * 5 + 0]));
    bool valid = (cx < sbnd[g*4+1]) && (cx > sbnd[g*4+0]) &&
                 (cy < sbnd[g*4+3]) && (cy > sbnd[g*4+2]);
    float sv = valid ? score : -1.0f;
    uint32_t dk = desc_key(sv);
    u64t ki = ((u64t)dk << 16) | (unsigned)i;
    const ulonglong2* skey2 = (const ulonglong2*)skey;
    int c = 0;
    int nit = Vpad >> 4;
    #pragma unroll 4
    for (int it = 0; it < nit; ++it) {
        ulonglong2 kj = skey2[it * 8 + jq];
        c += (kj.x < ki) + (kj.y < ki);
    }
    c += __shfl_xor(c, 1);
    c += __shfl_xor(c, 2);
    c += __shfl_xor(c, 4);
    if (jq == 0)
        scatter_one(i, c, ki, det, offsets, scales, boxes_srt, d_srt);
}

// mask build: block (bx,by): rows [bx*32,+32), words [by*16,+16)
__global__ __launch_bounds__(256) void k_mask(
    const float4* __restrict__ boxes_srt,
    const unsigned int* __restrict__ vcnt,
    u64t* __restrict__ mask)
{
    __shared__ float4 sb[16 * 65];
    __shared__ float  sa[16 * 65];
    int V = (int)*vcnt;
    int bx = blockIdx.x, by = blockIdx.y;
    if (bx * 32 >= V) return;
    if (by * 1024 >= V) return;
    if (by * 16 + 15 < (bx * 32) >> 6) return;
    int nc = (V + 63) >> 6;
    int tid = threadIdx.x;
    int cbase = by * 1024;
    for (int u = tid; u < 1024; u += 256) {
        float4 b = boxes_srt[cbase + u];
        int c = u >> 6, jj = u & 63;
        sb[c * 65 + jj] = b;
        sa[c * 65 + jj] = __fmul_rn(fmaxf(__fsub_rn(b.z, b.x), 0.0f),
                                    fmaxf(__fsub_rn(b.w, b.y), 0.0f));
    }
    __syncthreads();
    int r = bx * 32 + (tid >> 3);
    if (r >= V) return;
    float4 bi = boxes_srt[r];
    float ai = __fmul_rn(fmaxf(__fsub_rn(bi.z, bi.x), 0.0f),
                         fmaxf(__fsub_rn(bi.w, bi.y), 0.0f));
    int rw = r >> 6;
    #pragma unroll
    for (int k = 0; k < 2; ++k) {
        int wl = (tid & 7) + k * 8;
        int w = by * 16 + wl;
        if (w < rw || w >= nc) continue;
        u64t bits = 0;
        #pragma unroll 4
        for (int jj = 0; jj < 64; ++jj) {
            float4 bj = sb[wl * 65 + jj];
            float aj = sa[wl * 65 + jj];
            float iw = fmaxf(__fsub_rn(fminf(bi.z, bj.z), fmaxf(bi.x, bj.x)), 0.0f);
            float ih = fmaxf(__fsub_rn(fminf(bi.w, bj.w), fmaxf(bi.y, bj.y)), 0.0f);
            float inter = __fmul_rn(iw, ih);
            float uni   = __fsub_rn(__fadd_rn(ai, aj), inter);
            float iou   = __fdiv_rn(inter, fmaxf(uni, 1e-9f));
            int j = w * 64 + jj;
            if (j > r && iou > NMS_T) bits |= 1ull << jj;
        }
        mask[(size_t)r * 128 + w] = bits;
    }
}

// diag + carry-source word pairs for one 128-chunk (no row slots!)
struct WSlot { ulonglong2 dl, dh, n1l, n1h, n2l, n2h; };

__device__ __forceinline__ void fill_words(
    const u64t* __restrict__ mask, int lane, int T, WSlot& w)
{
    int rl = min(T * 128 + lane,      M_TOT - 1);
    int rh = min(T * 128 + 64 + lane, M_TOT - 1);
    const ulonglong2* mrl = (const ulonglong2*)(mask + (size_t)rl * 128);
    const ulonglong2* mrh = (const ulonglong2*)(mask + (size_t)rh * 128);
    int p0 = min(T,     63);
    int p1 = min(T + 1, 63);
    int p2 = min(T + 2, 63);
    w.dl  = mrl[p0]; w.dh  = mrh[p0];
    w.n1l = mrl[p1]; w.n1h = mrh[p1];
    w.n2l = mrl[p2]; w.n2h = mrh[p2];
}

// resolver: one 128-candidate chunk
__device__ __forceinline__ void res_step(
    const u64t* __restrict__ mask,
    u64t* sdead, u64t* ck, volatile int* res_prog, volatile int* h_prog,
    int lane, int nc, int T,
    u64t& cA_lo, u64t& cA_hi, u64t& cB_lo, u64t& cB_hi, WSlot& w)
{
    // spin until all chunks <= T-3 applied (h_prog[h] = smallest unapplied
    // owned chunk; condition "any hp < T-2" == "some chunk <= T-3 unapplied")
    if (T >= 3) {
        int need = T - 2;
        while (true) {
            int hp = (lane < 7) ? h_prog[lane] : 0x7FFFFFFF;
            if (__ballot(hp < need) == 0ull) break;
        }
    }
    // dead pair for this chunk (broadcast LDS read; includes V boundary init)
    u64t dlo = ((volatile u64t*)sdead)[2 * T];
    u64t dhi = ((volatile u64t*)sdead)[2 * T + 1];
    u64t live_lo = ~(dlo | cA_lo);
    u64t live_hi = ~(dhi | cA_hi);
    u64t km_lo = 0, km_hi = 0, c1l = 0, c1h = 0, c2l = 0, c2h = 0;
    while (live_lo | live_hi) {
        if (live_lo) {                    // wave-uniform branch
            int bs = __builtin_amdgcn_readfirstlane(__builtin_ctzll(live_lo));
            u64t rml = rdl64(w.dl.x, bs), rmh = rdl64(w.dl.y, bs);
            c1l |= rdl64(w.n1l.x, bs); c1h |= rdl64(w.n1l.y, bs);
            c2l |= rdl64(w.n2l.x, bs); c2h |= rdl64(w.n2l.y, bs);
            km_lo |= 1ull << bs;
            live_lo &= ~rml & ~(1ull << bs);
            live_hi &= ~rmh;
        } else {
            int bs = __builtin_amdgcn_readfirstlane(__builtin_ctzll(live_hi));
            u64t rmh = rdl64(w.dh.y, bs); // w.dh.x may be garbage: only hits
                                          // live_lo which is 0 here
            c1l |= rdl64(w.n1h.x, bs); c1h |= rdl64(w.n1h.y, bs);
            c2l |= rdl64(w.n2h.x, bs); c2h |= rdl64(w.n2h.y, bs);
            km_hi |= 1ull << bs;
            live_hi &= ~rmh & ~(1ull << bs);
        }
    }
    if (lane == 0) { ck[2 * T] = km_lo; ck[2 * T + 1] = km_hi; }
    __threadfence_block();
    if (lane == 0) *res_prog = T + 1;
    cA_lo = cB_lo | c1l; cA_hi = cB_hi | c1h;
    cB_lo = c2l;         cB_hi = c2h;
    fill_words(mask, lane, T + 3, w);     // prefetch slot for chunk T+3
}

__global__ __launch_bounds__(512) void k3_serial(
    const u64t* __restrict__ mask, const u64t* __restrict__ zrow,
    const float* __restrict__ d_srt, const unsigned int* __restrict__ vcnt,
    float* __restrict__ out)
{
    __shared__ u64t sdead[128];              // shared dead-vector (word i)
    __shared__ u64t ck[128];                 // per-64-word keptmask
    __shared__ int  res_prog;                // chunks published by resolver
    __shared__ int  h_prog[7];               // smallest unapplied owned chunk
    int tid = threadIdx.x, wv = tid >> 6, lane = tid & 63;
    int V = (int)*vcnt;
    int nc = (V + 127) >> 7;
    if (tid < 128) {
        int bw = tid * 64;
        u64t w0 = 0;
        if (bw >= V)           w0 = ~0ull;
        else if (bw + 64 > V)  w0 = (~0ull) << (V - bw);
        sdead[tid] = w0;
        ck[tid] = 0ull;
    }
    if (tid == 0) res_prog = 0;
    if (tid < 7)  h_prog[tid] = tid;         // helper h's first owned chunk
    __syncthreads();

    if (wv == 0) {
        // ---- resolver ----
        u64t cA_lo = 0, cA_hi = 0, cB_lo = 0, cB_hi = 0;
        WSlot WA, WB, WC;
        fill_words(mask, lane, 0, WA);
        fill_words(mask, lane, 1, WB);
        fill_words(mask, lane, 2, WC);
        for (int t = 0; t < nc; t += 3) {
            res_step(mask, sdead, ck, &res_prog, h_prog, lane, nc, t,
                     cA_lo, cA_hi, cB_lo, cB_hi, WA);
            if (t + 1 < nc)
                res_step(mask, sdead, ck, &res_prog, h_prog, lane, nc, t + 1,
                         cA_lo, cA_hi, cB_lo, cB_hi, WB);
            if (t + 2 < nc)
                res_step(mask, sdead, ck, &res_prog, h_prog, lane, nc, t + 2,
                         cA_lo, cA_hi, cB_lo, cB_hi, WC);
        }
    } else {
        // ---- helper (wv-1): chunks c == wv-1 (mod 7) ----
        int hh = wv - 1;
        for (int c = hh; c < nc; c += 7) {
            while (*(volatile int*)&res_prog <= c) __builtin_amdgcn_s_sleep(1);
            u64t kl = ((volatile u64t*)ck)[2 * c];
            u64t kh = ((volatile u64t*)ck)[2 * c + 1];
            if (kl | kh) {
                int base = c * 128;
                u64t ax = 0, ay = 0;
                while (kl | kh) {
                    ulonglong2 b[4];
                    #pragma unroll
                    for (int q = 0; q < 4; ++q) {   // 4-slot dummy-padded batch
                        const ulonglong2* ptr;
                        if (kl) {
                            int b_ = __builtin_ctzll(kl); kl &= kl - 1;
                            ptr = (const ulonglong2*)(mask + (size_t)(base + b_) * 128) + lane;
                        } else if (kh) {
                            int b_ = __builtin_ctzll(kh); kh &= kh - 1;
                            ptr = (const ulonglong2*)(mask + (size_t)(base + 64 + b_) * 128) + lane;
                        } else {
                            ptr = (const ulonglong2*)zrow + lane;
                        }
                        b[q] = *ptr;
                    }
                    ax |= b[0].x | b[1].x | b[2].x | b[3].x;
                    ay |= b[0].y | b[1].y | b[2].y | b[3].y;
                }
                atomicOr(&sdead[2 * lane],     ax);
                atomicOr(&sdead[2 * lane + 1], ay);
            }
            __threadfence_block();
            // all owned chunks < c+7 now applied (eager publish — the
            // round-10 deadlock was publishing only after the NEXT chunk)
            if (lane == 0) ((volatile int*)h_prog)[hh] = c + 7;
        }
        if (lane == 0) ((volatile int*)h_prog)[hh] = 0x7FFFFFFF;
    }
    __syncthreads();
    // output: expand keptmasks (order irrelevant for stores)
    if (tid < 128) {
        u64t m = ck[tid];
        while (m) {
            int b = __builtin_ctzll(m); m &= m - 1;
            int rr = tid * 64 + b;
            out[rr * 5 + 0] = d_srt[rr * 5 + 0];
            out[rr * 5 + 1] = d_srt[rr * 5 + 1];
            out[rr * 5 + 2] = d_srt[rr * 5 + 2];
            out[rr * 5 + 3] = d_srt[rr * 5 + 3];
            out[rr * 5 + 4] = d_srt[rr * 5 + 4];
        }
    }
}

extern "C" void kernel_launch(void* const* d_in, const int* in_sizes, int n_in,
                              void* d_out, int out_size, void* d_ws, size_t ws_size,
                              hipStream_t stream) {
    const float* det     = (const float*)d_in[0];
    const float* offsets = (const float*)d_in[1];
    const float* scales  = (const float*)d_in[2];
    const float* bounds  = (const float*)d_in[3];
    float* out = (float*)d_out;
    char* ws = (char*)d_ws;
    float4*       boxes = (float4*)(ws + WS_BOX);
    float*        d_srt = (float*)(ws + WS_D);
    unsigned int* vcnt  = (unsigned int*)(ws + WS_VCNT);
    u64t*         zrow  = (u64t*)(ws + WS_ZROW);
    u64t*         mask  = (u64t*)(ws + WS_MASK);

    k2_rank<<<256, 256, 0, stream>>>(det, offsets, scales, bounds, boxes, d_srt, vcnt, zrow, out);
    k_mask<<<dim3(256, 8), 256, 0, stream>>>(boxes, vcnt, mask);
    k3_serial<<<1, 512, 0, stream>>>(mask, zrow, d_srt, vcnt, out);
}

// Round 12
// 156.990 us; speedup vs baseline: 1.0319x; 1.0319x over previous
//
#include <hip/hip_runtime.h>
#include <cstdint>

// DetNet NMS, round 12.
// Round-11 post-mortem: k3 locked at ~500 cyc/keep across three structural
// memory-latency fixes => bottleneck is COMPUTE serialization: the resolve
// loop's wave-uniform values (live/km/carries) live in VGPRs (compiler can't
// prove uniformity), so ctz = v_ffbl chain, while(live) = v_cmp+exec branch,
// each step pays VALU latency + VALU->SGPR hazards.
// Fix: launder all uniform values through readfirstlane (-> SGPR class) so
// the resolve compiles to SALU (s_ff1_i32_b64 / s_andn2_b64 / s_cbranch,
// 1 cyc each); the only VALU op per keep is v_readlane. Carry readlanes
// moved off the per-keep chain into a post-resolve loop.
// Helper protocol / WSlot prefetch / k2 / k_mask identical to round 11
// (verified, absmax 0.0).

#define M_TOT 8192
#define NMS_T 0.3f

// ws layout (bytes)
#define WS_BOX   65536      // float4[8192]
#define WS_D     196608     // float[40960]
#define WS_VCNT  360448     // u32
#define WS_ZROW  393216     // u64[128] dummy zero row (zeroed by k2)
#define WS_MASK  524288     // u64[8192*128] = 8 MB

typedef unsigned long long u64t;

__device__ __forceinline__ uint32_t desc_key(float sv) {
    uint32_t u = __float_as_uint(sv);
    uint32_t m = (u & 0x80000000u) ? ~u : (u | 0x80000000u); // asc monotone
    return ~m;                                               // desc
}

// 64-bit broadcast, wave-uniform index: v_readlane -> SGPR pair (scalar class)
__device__ __forceinline__ u64t rdl64(u64t v, int sl) {
    unsigned lo = (unsigned)__builtin_amdgcn_readlane((int)(unsigned)v, sl);
    unsigned hi = (unsigned)__builtin_amdgcn_readlane((int)(unsigned)(v >> 32), sl);
    return ((u64t)hi << 32) | lo;
}
// launder a uniform 64-bit value into SGPR class (forces SALU downstream)
__device__ __forceinline__ u64t rdfl64(u64t v) {
    unsigned lo = (unsigned)__builtin_amdgcn_readfirstlane((int)(unsigned)v);
    unsigned hi = (unsigned)__builtin_amdgcn_readfirstlane((int)(unsigned)(v >> 32));
    return ((u64t)hi << 32) | lo;
}

__device__ __forceinline__ int scatter_one(
    int i, int rank, u64t key,
    const float* __restrict__ det, const float* __restrict__ offsets,
    const float* __restrict__ scales,
    float4* __restrict__ boxes_srt, float* __restrict__ d_srt)
{
    uint32_t dkey = (uint32_t)(key >> 16);
    if (dkey >= 0x7FFFFFFFu) return 0;   // score <= 0: row stays zero
    int g = i >> 10;
    float d0 = __fadd_rn(offsets[g*5+0], __fmul_rn(det[i*5+0], scales[g*5+0]));
    float d1 = __fadd_rn(offsets[g*5+1], __fmul_rn(det[i*5+1], scales[g*5+1]));
    float d2 = __fadd_rn(offsets[g*5+2], __fmul_rn(det[i*5+2], scales[g*5+2]));
    float d3 = __fadd_rn(offsets[g*5+3], __fmul_rn(det[i*5+3], scales[g*5+3]));
    float d4 = __fadd_rn(offsets[g*5+4], __fmul_rn(det[i*5+4], scales[g*5+4]));
    d_srt[rank*5+0] = d0; d_srt[rank*5+1] = d1; d_srt[rank*5+2] = d2;
    d_srt[rank*5+3] = d3; d_srt[rank*5+4] = d4;
    float hw = __fmul_rn(d3, 0.5f), hh = __fmul_rn(d4, 0.5f);
    boxes_srt[rank] = make_float4(__fsub_rn(d1, hw), __fsub_rn(d2, hh),
                                  __fadd_rn(d1, hw), __fadd_rn(d2, hh));
    return 1;
}

__global__ __launch_bounds__(256) void k2_rank(
    const float* __restrict__ det, const float* __restrict__ offsets,
    const float* __restrict__ scales, const float* __restrict__ bounds,
    float4* __restrict__ boxes_srt, float* __restrict__ d_srt,
    unsigned int* __restrict__ vcnt, u64t* __restrict__ zrow,
    float* __restrict__ out)
{
    __shared__ u64t skey[M_TOT];
    __shared__ float soff[40], sscl[40], sbnd[32];
    __shared__ int sTop;
    int t = threadIdx.x;
    int lane = t & 63;
    if (t == 0) sTop = 0;
    if (t < 40) { soff[t] = offsets[t]; sscl[t] = scales[t]; }
    if (t < 32) { sbnd[t] = bounds[t]; }
    if (blockIdx.x == 0 && t < 128) zrow[t] = 0ull;
    __syncthreads();

    #pragma unroll 4
    for (int s = 0; s < 32; ++s) {
        int u = s * 256 + t;
        int g = u >> 10;
        float raw_s = det[u * 5 + 0];
        float cx    = det[u * 5 + 1];
        float cy    = det[u * 5 + 2];
        float score = __fadd_rn(soff[g * 5 + 0], __fmul_rn(raw_s, sscl[g * 5 + 0]));
        bool valid = (cx < sbnd[g*4+1]) && (cx > sbnd[g*4+0]) &&
                     (cy < sbnd[g*4+3]) && (cy > sbnd[g*4+2]);
        float sv = valid ? score : -1.0f;
        uint32_t dk = desc_key(sv);
        bool push = dk < 0x7FFFFFFFu;
        u64t key = ((u64t)dk << 16) | (unsigned)u;
        u64t bal = __ballot(push);
        if (bal) {
            int lw = 0;
            if (lane == 0) lw = atomicAdd(&sTop, __popcll(bal));
            int wbase = __builtin_amdgcn_readfirstlane(lw);
            if (push) {
                int off = __popcll(bal & ((1ull << lane) - 1ull));
                skey[wbase + off] = key;
            }
        }
    }
    __syncthreads();
    int V = sTop;
    int Vpad = (V + 15) & ~15;
    if (t < Vpad - V) skey[V + t] = ~0ull;
    {
        int zb = blockIdx.x * 160;
        for (int z = zb + t; z < zb + 160; z += 256) out[z] = 0.0f;
    }
    __syncthreads();
    if (t == 0) *vcnt = (unsigned)V;

    int grp = t >> 3;
    int jq  = t & 7;
    int i = blockIdx.x * 32 + grp;
    int g = i >> 10;
    float raw_s = det[i * 5 + 0];
    float cx    = det[i * 5 + 1];
    float cy    = det[i * 5 + 2];
    float score = __fadd_rn(soff[g * 5 + 0], __fmul_rn(raw_s, sscl[g * 5 + 0]));
    bool valid = (cx < sbnd[g*4+1]) && (cx > sbnd[g*4+0]) &&
                 (cy < sbnd[g*4+3]) && (cy > sbnd[g*4+2]);
    float sv = valid ? score : -1.0f;
    uint32_t dk = desc_key(sv);
    u64t ki = ((u64t)dk << 16) | (unsigned)i;
    const ulonglong2* skey2 = (const ulonglong2*)skey;
    int c = 0;
    int nit = Vpad >> 4;
    #pragma unroll 4
    for (int it = 0; it < nit; ++it) {
        ulonglong2 kj = skey2[it * 8 + jq];
        c += (kj.x < ki) + (kj.y < ki);
    }
    c += __shfl_xor(c, 1);
    c += __shfl_xor(c, 2);
    c += __shfl_xor(c, 4);
    if (jq == 0)
        scatter_one(i, c, ki, det, offsets, scales, boxes_srt, d_srt);
}

// mask build: block (bx,by): rows [bx*32,+32), words [by*16,+16)
__global__ __launch_bounds__(256) void k_mask(
    const float4* __restrict__ boxes_srt,
    const unsigned int* __restrict__ vcnt,
    u64t* __restrict__ mask)
{
    __shared__ float4 sb[16 * 65];
    __shared__ float  sa[16 * 65];
    int V = (int)*vcnt;
    int bx = blockIdx.x, by = blockIdx.y;
    if (bx * 32 >= V) return;
    if (by * 1024 >= V) return;
    if (by * 16 + 15 < (bx * 32) >> 6) return;
    int nc = (V + 63) >> 6;
    int tid = threadIdx.x;
    int cbase = by * 1024;
    for (int u = tid; u < 1024; u += 256) {
        float4 b = boxes_srt[cbase + u];
        int c = u >> 6, jj = u & 63;
        sb[c * 65 + jj] = b;
        sa[c * 65 + jj] = __fmul_rn(fmaxf(__fsub_rn(b.z, b.x), 0.0f),
                                    fmaxf(__fsub_rn(b.w, b.y), 0.0f));
    }
    __syncthreads();
    int r = bx * 32 + (tid >> 3);
    if (r >= V) return;
    float4 bi = boxes_srt[r];
    float ai = __fmul_rn(fmaxf(__fsub_rn(bi.z, bi.x), 0.0f),
                         fmaxf(__fsub_rn(bi.w, bi.y), 0.0f));
    int rw = r >> 6;
    #pragma unroll
    for (int k = 0; k < 2; ++k) {
        int wl = (tid & 7) + k * 8;
        int w = by * 16 + wl;
        if (w < rw || w >= nc) continue;
        u64t bits = 0;
        #pragma unroll 4
        for (int jj = 0; jj < 64; ++jj) {
            float4 bj = sb[wl * 65 + jj];
            float aj = sa[wl * 65 + jj];
            float iw = fmaxf(__fsub_rn(fminf(bi.z, bj.z), fmaxf(bi.x, bj.x)), 0.0f);
            float ih = fmaxf(__fsub_rn(fminf(bi.w, bj.w), fmaxf(bi.y, bj.y)), 0.0f);
            float inter = __fmul_rn(iw, ih);
            float uni   = __fsub_rn(__fadd_rn(ai, aj), inter);
            float iou   = __fdiv_rn(inter, fmaxf(uni, 1e-9f));
            int j = w * 64 + jj;
            if (j > r && iou > NMS_T) bits |= 1ull << jj;
        }
        mask[(size_t)r * 128 + w] = bits;
    }
}

// diag + carry-source word pairs for one 128-chunk
struct WSlot { ulonglong2 dl, dh, n1l, n1h, n2l, n2h; };

__device__ __forceinline__ void fill_words(
    const u64t* __restrict__ mask, int lane, int T, WSlot& w)
{
    int rl = min(T * 128 + lane,      M_TOT - 1);
    int rh = min(T * 128 + 64 + lane, M_TOT - 1);
    const ulonglong2* mrl = (const ulonglong2*)(mask + (size_t)rl * 128);
    const ulonglong2* mrh = (const ulonglong2*)(mask + (size_t)rh * 128);
    int p0 = min(T,     63);
    int p1 = min(T + 1, 63);
    int p2 = min(T + 2, 63);
    w.dl  = mrl[p0]; w.dh  = mrh[p0];
    w.n1l = mrl[p1]; w.n1h = mrh[p1];
    w.n2l = mrl[p2]; w.n2h = mrh[p2];
}

// resolver: one 128-candidate chunk; resolve loop is pure SALU + v_readlane
__device__ __forceinline__ void res_step(
    const u64t* __restrict__ mask,
    u64t* sdead, u64t* ck, volatile int* res_prog, volatile int* h_prog,
    int lane, int nc, int T,
    u64t& cA_lo, u64t& cA_hi, u64t& cB_lo, u64t& cB_hi, WSlot& w)
{
    // spin until all chunks <= T-3 applied
    if (T >= 3) {
        int need = T - 2;
        while (true) {
            int hp = (lane < 7) ? h_prog[lane] : 0x7FFFFFFF;
            if (__ballot(hp < need) == 0ull) break;
        }
    }
    // dead pair (LDS read, then laundered to SGPRs)
    u64t dlo = rdfl64(((volatile u64t*)sdead)[2 * T]);
    u64t dhi = rdfl64(((volatile u64t*)sdead)[2 * T + 1]);
    u64t live_lo = ~(dlo | cA_lo);       // all-scalar from here
    u64t live_hi = ~(dhi | cA_hi);
    u64t km_lo = 0, km_hi = 0;
    // low-word resolve: s_ff1 -> v_readlane x2 -> s_andn2 per keep
    while (live_lo) {
        int bs = (int)__builtin_ctzll(live_lo);
        km_lo |= 1ull << bs;
        u64t rml = rdl64(w.dl.x, bs);
        u64t rmh = rdl64(w.dl.y, bs);
        live_lo &= ~rml & ~(1ull << bs);
        live_hi &= ~rmh;
    }
    // high-word resolve (w.dh.x may be garbage: only affects low word,
    // already fully resolved/consumed)
    while (live_hi) {
        int bs = (int)__builtin_ctzll(live_hi);
        km_hi |= 1ull << bs;
        u64t rmh = rdl64(w.dh.y, bs);
        live_hi &= ~rmh & ~(1ull << bs);
    }
    if (lane == 0) { ck[2 * T] = km_lo; ck[2 * T + 1] = km_hi; }
    __threadfence_block();
    if (lane == 0) *res_prog = T + 1;
    // carries (off the per-keep chain; readlanes independent, pipelined)
    u64t c1l = 0, c1h = 0, c2l = 0, c2h = 0;
    u64t km = km_lo;
    while (km) {
        int b = (int)__builtin_ctzll(km); km &= km - 1;
        c1l |= rdl64(w.n1l.x, b); c1h |= rdl64(w.n1l.y, b);
        c2l |= rdl64(w.n2l.x, b); c2h |= rdl64(w.n2l.y, b);
    }
    km = km_hi;
    while (km) {
        int b = (int)__builtin_ctzll(km); km &= km - 1;
        c1l |= rdl64(w.n1h.x, b); c1h |= rdl64(w.n1h.y, b);
        c2l |= rdl64(w.n2h.x, b); c2h |= rdl64(w.n2h.y, b);
    }
    cA_lo = cB_lo | c1l; cA_hi = cB_hi | c1h;
    cB_lo = c2l;         cB_hi = c2h;
    fill_words(mask, lane, T + 3, w);     // prefetch slot for chunk T+3
}

__global__ __launch_bounds__(512) void k3_serial(
    const u64t* __restrict__ mask, const u64t* __restrict__ zrow,
    const float* __restrict__ d_srt, const unsigned int* __restrict__ vcnt,
    float* __restrict__ out)
{
    __shared__ u64t sdead[128];              // shared dead-vector (word i)
    __shared__ u64t ck[128];                 // per-64-word keptmask
    __shared__ int  res_prog;                // chunks published by resolver
    __shared__ int  h_prog[7];               // smallest unapplied owned chunk
    int tid = threadIdx.x, wv = tid >> 6, lane = tid & 63;
    int V = (int)*vcnt;
    int nc = (V + 127) >> 7;
    if (tid < 128) {
        int bw = tid * 64;
        u64t w0 = 0;
        if (bw >= V)           w0 = ~0ull;
        else if (bw + 64 > V)  w0 = (~0ull) << (V - bw);
        sdead[tid] = w0;
        ck[tid] = 0ull;
    }
    if (tid == 0) res_prog = 0;
    if (tid < 7)  h_prog[tid] = tid;
    __syncthreads();

    if (wv == 0) {
        // ---- resolver ----
        u64t cA_lo = 0, cA_hi = 0, cB_lo = 0, cB_hi = 0;
        WSlot WA, WB, WC;
        fill_words(mask, lane, 0, WA);
        fill_words(mask, lane, 1, WB);
        fill_words(mask, lane, 2, WC);
        for (int t = 0; t < nc; t += 3) {
            res_step(mask, sdead, ck, &res_prog, h_prog, lane, nc, t,
                     cA_lo, cA_hi, cB_lo, cB_hi, WA);
            if (t + 1 < nc)
                res_step(mask, sdead, ck, &res_prog, h_prog, lane, nc, t + 1,
                         cA_lo, cA_hi, cB_lo, cB_hi, WB);
            if (t + 2 < nc)
                res_step(mask, sdead, ck, &res_prog, h_prog, lane, nc, t + 2,
                         cA_lo, cA_hi, cB_lo, cB_hi, WC);
        }
    } else {
        // ---- helper (wv-1): chunks c == wv-1 (mod 7) ----
        int hh = wv - 1;
        for (int c = hh; c < nc; c += 7) {
            while (*(volatile int*)&res_prog <= c) __builtin_amdgcn_s_sleep(1);
            u64t kl = ((volatile u64t*)ck)[2 * c];
            u64t kh = ((volatile u64t*)ck)[2 * c + 1];
            if (kl | kh) {
                int base = c * 128;
                u64t ax = 0, ay = 0;
                while (kl | kh) {
                    ulonglong2 b[4];
                    #pragma unroll
                    for (int q = 0; q < 4; ++q) {   // 4-slot dummy-padded batch
                        const ulonglong2* ptr;
                        if (kl) {
                            int b_ = __builtin_ctzll(kl); kl &= kl - 1;
                            ptr = (const ulonglong2*)(mask + (size_t)(base + b_) * 128) + lane;
                        } else if (kh) {
                            int b_ = __builtin_ctzll(kh); kh &= kh - 1;
                            ptr = (const ulonglong2*)(mask + (size_t)(base + 64 + b_) * 128) + lane;
                        } else {
                            ptr = (const ulonglong2*)zrow + lane;
                        }
                        b[q] = *ptr;
                    }
                    ax |= b[0].x | b[1].x | b[2].x | b[3].x;
                    ay |= b[0].y | b[1].y | b[2].y | b[3].y;
                }
                atomicOr(&sdead[2 * lane],     ax);
                atomicOr(&sdead[2 * lane + 1], ay);
            }
            __threadfence_block();
            if (lane == 0) ((volatile int*)h_prog)[hh] = c + 7;
        }
        if (lane == 0) ((volatile int*)h_prog)[hh] = 0x7FFFFFFF;
    }
    __syncthreads();
    // output: expand keptmasks (order irrelevant for stores)
    if (tid < 128) {
        u64t m = ck[tid];
        while (m) {
            int b = __builtin_ctzll(m); m &= m - 1;
            int rr = tid * 64 + b;
            out[rr * 5 + 0] = d_srt[rr * 5 + 0];
            out[rr * 5 + 1] = d_srt[rr * 5 + 1];
            out[rr * 5 + 2] = d_srt[rr * 5 + 2];
            out[rr * 5 + 3] = d_srt[rr * 5 + 3];
            out[rr * 5 + 4] = d_srt[rr * 5 + 4];
        }
    }
}

extern "C" void kernel_launch(void* const* d_in, const int* in_sizes, int n_in,
                              void* d_out, int out_size, void* d_ws, size_t ws_size,
                              hipStream_t stream) {
    const float* det     = (const float*)d_in[0];
    const float* offsets = (const float*)d_in[1];
    const float* scales  = (const float*)d_in[2];
    const float* bounds  = (const float*)d_in[3];
    float* out = (float*)d_out;
    char* ws = (char*)d_ws;
    float4*       boxes = (float4*)(ws + WS_BOX);
    float*        d_srt = (float*)(ws + WS_D);
    unsigned int* vcnt  = (unsigned int*)(ws + WS_VCNT);
    u64t*         zrow  = (u64t*)(ws + WS_ZROW);
    u64t*         mask  = (u64t*)(ws + WS_MASK);

    k2_rank<<<256, 256, 0, stream>>>(det, offsets, scales, bounds, boxes, d_srt, vcnt, zrow, out);
    k_mask<<<dim3(256, 8), 256, 0, stream>>>(boxes, vcnt, mask);
    k3_serial<<<1, 512, 0, stream>>>(mask, zrow, d_srt, vcnt, out);
}

// Round 13
// 154.840 us; speedup vs baseline: 1.0462x; 1.0139x over previous
//
#include <hip/hip_runtime.h>
#include <cstdint>

// DetNet NMS, round 13.
// Round-12 post-mortem: k3 pinned at ~3400 cyc/chunk across FOUR structural
// fixes, and VGPR_Count=40 < declared pipeline state (72+ regs of WSlots).
// The allocator (no waves-per-EU hint -> occupancy-targeting) demoted every
// prefetch to load-at-use; all pipelining since r6 was silently deleted.
// Fix (single change): __launch_bounds__(512, 2) on k3_serial -> VGPR cap
// 256/wave (8 waves = 2/SIMD x 256 = full pool), WSlot state stays resident,
// the depth-3 prefetch becomes real.
// Everything else identical to round 12 (verified, absmax 0.0).

#define M_TOT 8192
#define NMS_T 0.3f

// ws layout (bytes)
#define WS_BOX   65536      // float4[8192]
#define WS_D     196608     // float[40960]
#define WS_VCNT  360448     // u32
#define WS_ZROW  393216     // u64[128] dummy zero row (zeroed by k2)
#define WS_MASK  524288     // u64[8192*128] = 8 MB

typedef unsigned long long u64t;

__device__ __forceinline__ uint32_t desc_key(float sv) {
    uint32_t u = __float_as_uint(sv);
    uint32_t m = (u & 0x80000000u) ? ~u : (u | 0x80000000u); // asc monotone
    return ~m;                                               // desc
}

// 64-bit broadcast, wave-uniform index: v_readlane -> SGPR pair
__device__ __forceinline__ u64t rdl64(u64t v, int sl) {
    unsigned lo = (unsigned)__builtin_amdgcn_readlane((int)(unsigned)v, sl);
    unsigned hi = (unsigned)__builtin_amdgcn_readlane((int)(unsigned)(v >> 32), sl);
    return ((u64t)hi << 32) | lo;
}
// launder a uniform 64-bit value into SGPR class (forces SALU downstream)
__device__ __forceinline__ u64t rdfl64(u64t v) {
    unsigned lo = (unsigned)__builtin_amdgcn_readfirstlane((int)(unsigned)v);
    unsigned hi = (unsigned)__builtin_amdgcn_readfirstlane((int)(unsigned)(v >> 32));
    return ((u64t)hi << 32) | lo;
}

__device__ __forceinline__ int scatter_one(
    int i, int rank, u64t key,
    const float* __restrict__ det, const float* __restrict__ offsets,
    const float* __restrict__ scales,
    float4* __restrict__ boxes_srt, float* __restrict__ d_srt)
{
    uint32_t dkey = (uint32_t)(key >> 16);
    if (dkey >= 0x7FFFFFFFu) return 0;   // score <= 0: row stays zero
    int g = i >> 10;
    float d0 = __fadd_rn(offsets[g*5+0], __fmul_rn(det[i*5+0], scales[g*5+0]));
    float d1 = __fadd_rn(offsets[g*5+1], __fmul_rn(det[i*5+1], scales[g*5+1]));
    float d2 = __fadd_rn(offsets[g*5+2], __fmul_rn(det[i*5+2], scales[g*5+2]));
    float d3 = __fadd_rn(offsets[g*5+3], __fmul_rn(det[i*5+3], scales[g*5+3]));
    float d4 = __fadd_rn(offsets[g*5+4], __fmul_rn(det[i*5+4], scales[g*5+4]));
    d_srt[rank*5+0] = d0; d_srt[rank*5+1] = d1; d_srt[rank*5+2] = d2;
    d_srt[rank*5+3] = d3; d_srt[rank*5+4] = d4;
    float hw = __fmul_rn(d3, 0.5f), hh = __fmul_rn(d4, 0.5f);
    boxes_srt[rank] = make_float4(__fsub_rn(d1, hw), __fsub_rn(d2, hh),
                                  __fadd_rn(d1, hw), __fadd_rn(d2, hh));
    return 1;
}

__global__ __launch_bounds__(256) void k2_rank(
    const float* __restrict__ det, const float* __restrict__ offsets,
    const float* __restrict__ scales, const float* __restrict__ bounds,
    float4* __restrict__ boxes_srt, float* __restrict__ d_srt,
    unsigned int* __restrict__ vcnt, u64t* __restrict__ zrow,
    float* __restrict__ out)
{
    __shared__ u64t skey[M_TOT];
    __shared__ float soff[40], sscl[40], sbnd[32];
    __shared__ int sTop;
    int t = threadIdx.x;
    int lane = t & 63;
    if (t == 0) sTop = 0;
    if (t < 40) { soff[t] = offsets[t]; sscl[t] = scales[t]; }
    if (t < 32) { sbnd[t] = bounds[t]; }
    if (blockIdx.x == 0 && t < 128) zrow[t] = 0ull;
    __syncthreads();

    #pragma unroll 4
    for (int s = 0; s < 32; ++s) {
        int u = s * 256 + t;
        int g = u >> 10;
        float raw_s = det[u * 5 + 0];
        float cx    = det[u * 5 + 1];
        float cy    = det[u * 5 + 2];
        float score = __fadd_rn(soff[g * 5 + 0], __fmul_rn(raw_s, sscl[g * 5 + 0]));
        bool valid = (cx < sbnd[g*4+1]) && (cx > sbnd[g*4+0]) &&
                     (cy < sbnd[g*4+3]) && (cy > sbnd[g*4+2]);
        float sv = valid ? score : -1.0f;
        uint32_t dk = desc_key(sv);
        bool push = dk < 0x7FFFFFFFu;
        u64t key = ((u64t)dk << 16) | (unsigned)u;
        u64t bal = __ballot(push);
        if (bal) {
            int lw = 0;
            if (lane == 0) lw = atomicAdd(&sTop, __popcll(bal));
            int wbase = __builtin_amdgcn_readfirstlane(lw);
            if (push) {
                int off = __popcll(bal & ((1ull << lane) - 1ull));
                skey[wbase + off] = key;
            }
        }
    }
    __syncthreads();
    int V = sTop;
    int Vpad = (V + 15) & ~15;
    if (t < Vpad - V) skey[V + t] = ~0ull;
    {
        int zb = blockIdx.x * 160;
        for (int z = zb + t; z < zb + 160; z += 256) out[z] = 0.0f;
    }
    __syncthreads();
    if (t == 0) *vcnt = (unsigned)V;

    int grp = t >> 3;
    int jq  = t & 7;
    int i = blockIdx.x * 32 + grp;
    int g = i >> 10;
    float raw_s = det[i * 5 + 0];
    float cx    = det[i * 5 + 1];
    float cy    = det[i * 5 + 2];
    float score = __fadd_rn(soff[g * 5 + 0], __fmul_rn(raw_s, sscl[g * 5 + 0]));
    bool valid = (cx < sbnd[g*4+1]) && (cx > sbnd[g*4+0]) &&
                 (cy < sbnd[g*4+3]) && (cy > sbnd[g*4+2]);
    float sv = valid ? score : -1.0f;
    uint32_t dk = desc_key(sv);
    u64t ki = ((u64t)dk << 16) | (unsigned)i;
    const ulonglong2* skey2 = (const ulonglong2*)skey;
    int c = 0;
    int nit = Vpad >> 4;
    #pragma unroll 4
    for (int it = 0; it < nit; ++it) {
        ulonglong2 kj = skey2[it * 8 + jq];
        c += (kj.x < ki) + (kj.y < ki);
    }
    c += __shfl_xor(c, 1);
    c += __shfl_xor(c, 2);
    c += __shfl_xor(c, 4);
    if (jq == 0)
        scatter_one(i, c, ki, det, offsets, scales, boxes_srt, d_srt);
}

// mask build: block (bx,by): rows [bx*32,+32), words [by*16,+16)
__global__ __launch_bounds__(256) void k_mask(
    const float4* __restrict__ boxes_srt,
    const unsigned int* __restrict__ vcnt,
    u64t* __restrict__ mask)
{
    __shared__ float4 sb[16 * 65];
    __shared__ float  sa[16 * 65];
    int V = (int)*vcnt;
    int bx = blockIdx.x, by = blockIdx.y;
    if (bx * 32 >= V) return;
    if (by * 1024 >= V) return;
    if (by * 16 + 15 < (bx * 32) >> 6) return;
    int nc = (V + 63) >> 6;
    int tid = threadIdx.x;
    int cbase = by * 1024;
    for (int u = tid; u < 1024; u += 256) {
        float4 b = boxes_srt[cbase + u];
        int c = u >> 6, jj = u & 63;
        sb[c * 65 + jj] = b;
        sa[c * 65 + jj] = __fmul_rn(fmaxf(__fsub_rn(b.z, b.x), 0.0f),
                                    fmaxf(__fsub_rn(b.w, b.y), 0.0f));
    }
    __syncthreads();
    int r = bx * 32 + (tid >> 3);
    if (r >= V) return;
    float4 bi = boxes_srt[r];
    float ai = __fmul_rn(fmaxf(__fsub_rn(bi.z, bi.x), 0.0f),
                         fmaxf(__fsub_rn(bi.w, bi.y), 0.0f));
    int rw = r >> 6;
    #pragma unroll
    for (int k = 0; k < 2; ++k) {
        int wl = (tid & 7) + k * 8;
        int w = by * 16 + wl;
        if (w < rw || w >= nc) continue;
        u64t bits = 0;
        #pragma unroll 4
        for (int jj = 0; jj < 64; ++jj) {
            float4 bj = sb[wl * 65 + jj];
            float aj = sa[wl * 65 + jj];
            float iw = fmaxf(__fsub_rn(fminf(bi.z, bj.z), fmaxf(bi.x, bj.x)), 0.0f);
            float ih = fmaxf(__fsub_rn(fminf(bi.w, bj.w), fmaxf(bi.y, bj.y)), 0.0f);
            float inter = __fmul_rn(iw, ih);
            float uni   = __fsub_rn(__fadd_rn(ai, aj), inter);
            float iou   = __fdiv_rn(inter, fmaxf(uni, 1e-9f));
            int j = w * 64 + jj;
            if (j > r && iou > NMS_T) bits |= 1ull << jj;
        }
        mask[(size_t)r * 128 + w] = bits;
    }
}

// diag + carry-source word pairs for one 128-chunk
struct WSlot { ulonglong2 dl, dh, n1l, n1h, n2l, n2h; };

__device__ __forceinline__ void fill_words(
    const u64t* __restrict__ mask, int lane, int T, WSlot& w)
{
    int rl = min(T * 128 + lane,      M_TOT - 1);
    int rh = min(T * 128 + 64 + lane, M_TOT - 1);
    const ulonglong2* mrl = (const ulonglong2*)(mask + (size_t)rl * 128);
    const ulonglong2* mrh = (const ulonglong2*)(mask + (size_t)rh * 128);
    int p0 = min(T,     63);
    int p1 = min(T + 1, 63);
    int p2 = min(T + 2, 63);
    w.dl  = mrl[p0]; w.dh  = mrh[p0];
    w.n1l = mrl[p1]; w.n1h = mrh[p1];
    w.n2l = mrl[p2]; w.n2h = mrh[p2];
}

// resolver: one 128-candidate chunk; resolve loop is pure SALU + v_readlane
__device__ __forceinline__ void res_step(
    const u64t* __restrict__ mask,
    u64t* sdead, u64t* ck, volatile int* res_prog, volatile int* h_prog,
    int lane, int nc, int T,
    u64t& cA_lo, u64t& cA_hi, u64t& cB_lo, u64t& cB_hi, WSlot& w)
{
    // spin until all chunks <= T-3 applied
    if (T >= 3) {
        int need = T - 2;
        while (true) {
            int hp = (lane < 7) ? h_prog[lane] : 0x7FFFFFFF;
            if (__ballot(hp < need) == 0ull) break;
        }
    }
    // dead pair (LDS read, then laundered to SGPRs)
    u64t dlo = rdfl64(((volatile u64t*)sdead)[2 * T]);
    u64t dhi = rdfl64(((volatile u64t*)sdead)[2 * T + 1]);
    u64t live_lo = ~(dlo | cA_lo);       // all-scalar from here
    u64t live_hi = ~(dhi | cA_hi);
    u64t km_lo = 0, km_hi = 0;
    // low-word resolve: s_ff1 -> v_readlane x2 -> s_andn2 per keep
    while (live_lo) {
        int bs = (int)__builtin_ctzll(live_lo);
        km_lo |= 1ull << bs;
        u64t rml = rdl64(w.dl.x, bs);
        u64t rmh = rdl64(w.dl.y, bs);
        live_lo &= ~rml & ~(1ull << bs);
        live_hi &= ~rmh;
    }
    // high-word resolve (w.dh.x may be garbage: only affects low word,
    // already fully resolved/consumed)
    while (live_hi) {
        int bs = (int)__builtin_ctzll(live_hi);
        km_hi |= 1ull << bs;
        u64t rmh = rdl64(w.dh.y, bs);
        live_hi &= ~rmh & ~(1ull << bs);
    }
    if (lane == 0) { ck[2 * T] = km_lo; ck[2 * T + 1] = km_hi; }
    __threadfence_block();
    if (lane == 0) *res_prog = T + 1;
    // carries (off the per-keep chain; readlanes independent, pipelined)
    u64t c1l = 0, c1h = 0, c2l = 0, c2h = 0;
    u64t km = km_lo;
    while (km) {
        int b = (int)__builtin_ctzll(km); km &= km - 1;
        c1l |= rdl64(w.n1l.x, b); c1h |= rdl64(w.n1l.y, b);
        c2l |= rdl64(w.n2l.x, b); c2h |= rdl64(w.n2l.y, b);
    }
    km = km_hi;
    while (km) {
        int b = (int)__builtin_ctzll(km); km &= km - 1;
        c1l |= rdl64(w.n1h.x, b); c1h |= rdl64(w.n1h.y, b);
        c2l |= rdl64(w.n2h.x, b); c2h |= rdl64(w.n2h.y, b);
    }
    cA_lo = cB_lo | c1l; cA_hi = cB_hi | c1h;
    cB_lo = c2l;         cB_hi = c2h;
    fill_words(mask, lane, T + 3, w);     // prefetch slot for chunk T+3
}

// (512, 2): min 2 waves/EU -> VGPR cap 256/wave; 8 waves fit (2/SIMD x 256).
// Round-12's default hint gave VGPR_Count=40 -> WSlot state demoted to
// load-at-use -> every chunk ate full memory latency serially.
__global__ __launch_bounds__(512, 2) void k3_serial(
    const u64t* __restrict__ mask, const u64t* __restrict__ zrow,
    const float* __restrict__ d_srt, const unsigned int* __restrict__ vcnt,
    float* __restrict__ out)
{
    __shared__ u64t sdead[128];              // shared dead-vector (word i)
    __shared__ u64t ck[128];                 // per-64-word keptmask
    __shared__ int  res_prog;                // chunks published by resolver
    __shared__ int  h_prog[7];               // smallest unapplied owned chunk
    int tid = threadIdx.x, wv = tid >> 6, lane = tid & 63;
    int V = (int)*vcnt;
    int nc = (V + 127) >> 7;
    if (tid < 128) {
        int bw = tid * 64;
        u64t w0 = 0;
        if (bw >= V)           w0 = ~0ull;
        else if (bw + 64 > V)  w0 = (~0ull) << (V - bw);
        sdead[tid] = w0;
        ck[tid] = 0ull;
    }
    if (tid == 0) res_prog = 0;
    if (tid < 7)  h_prog[tid] = tid;
    __syncthreads();

    if (wv == 0) {
        // ---- resolver ----
        u64t cA_lo = 0, cA_hi = 0, cB_lo = 0, cB_hi = 0;
        WSlot WA, WB, WC;
        fill_words(mask, lane, 0, WA);
        fill_words(mask, lane, 1, WB);
        fill_words(mask, lane, 2, WC);
        for (int t = 0; t < nc; t += 3) {
            res_step(mask, sdead, ck, &res_prog, h_prog, lane, nc, t,
                     cA_lo, cA_hi, cB_lo, cB_hi, WA);
            if (t + 1 < nc)
                res_step(mask, sdead, ck, &res_prog, h_prog, lane, nc, t + 1,
                         cA_lo, cA_hi, cB_lo, cB_hi, WB);
            if (t + 2 < nc)
                res_step(mask, sdead, ck, &res_prog, h_prog, lane, nc, t + 2,
                         cA_lo, cA_hi, cB_lo, cB_hi, WC);
        }
    } else {
        // ---- helper (wv-1): chunks c == wv-1 (mod 7) ----
        int hh = wv - 1;
        for (int c = hh; c < nc; c += 7) {
            while (*(volatile int*)&res_prog <= c) __builtin_amdgcn_s_sleep(1);
            u64t kl = ((volatile u64t*)ck)[2 * c];
            u64t kh = ((volatile u64t*)ck)[2 * c + 1];
            if (kl | kh) {
                int base = c * 128;
                u64t ax = 0, ay = 0;
                while (kl | kh) {
                    ulonglong2 b[4];
                    #pragma unroll
                    for (int q = 0; q < 4; ++q) {   // 4-slot dummy-padded batch
                        const ulonglong2* ptr;
                        if (kl) {
                            int b_ = __builtin_ctzll(kl); kl &= kl - 1;
                            ptr = (const ulonglong2*)(mask + (size_t)(base + b_) * 128) + lane;
                        } else if (kh) {
                            int b_ = __builtin_ctzll(kh); kh &= kh - 1;
                            ptr = (const ulonglong2*)(mask + (size_t)(base + 64 + b_) * 128) + lane;
                        } else {
                            ptr = (const ulonglong2*)zrow + lane;
                        }
                        b[q] = *ptr;
                    }
                    ax |= b[0].x | b[1].x | b[2].x | b[3].x;
                    ay |= b[0].y | b[1].y | b[2].y | b[3].y;
                }
                atomicOr(&sdead[2 * lane],     ax);
                atomicOr(&sdead[2 * lane + 1], ay);
            }
            __threadfence_block();
            if (lane == 0) ((volatile int*)h_prog)[hh] = c + 7;
        }
        if (lane == 0) ((volatile int*)h_prog)[hh] = 0x7FFFFFFF;
    }
    __syncthreads();
    // output: expand keptmasks (order irrelevant for stores)
    if (tid < 128) {
        u64t m = ck[tid];
        while (m) {
            int b = __builtin_ctzll(m); m &= m - 1;
            int rr = tid * 64 + b;
            out[rr * 5 + 0] = d_srt[rr * 5 + 0];
            out[rr * 5 + 1] = d_srt[rr * 5 + 1];
            out[rr * 5 + 2] = d_srt[rr * 5 + 2];
            out[rr * 5 + 3] = d_srt[rr * 5 + 3];
            out[rr * 5 + 4] = d_srt[rr * 5 + 4];
        }
    }
}

extern "C" void kernel_launch(void* const* d_in, const int* in_sizes, int n_in,
                              void* d_out, int out_size, void* d_ws, size_t ws_size,
                              hipStream_t stream) {
    const float* det     = (const float*)d_in[0];
    const float* offsets = (const float*)d_in[1];
    const float* scales  = (const float*)d_in[2];
    const float* bounds  = (const float*)d_in[3];
    float* out = (float*)d_out;
    char* ws = (char*)d_ws;
    float4*       boxes = (float4*)(ws + WS_BOX);
    float*        d_srt = (float*)(ws + WS_D);
    unsigned int* vcnt  = (unsigned int*)(ws + WS_VCNT);
    u64t*         zrow  = (u64t*)(ws + WS_ZROW);
    u64t*         mask  = (u64t*)(ws + WS_MASK);

    k2_rank<<<256, 256, 0, stream>>>(det, offsets, scales, bounds, boxes, d_srt, vcnt, zrow, out);
    k_mask<<<dim3(256, 8), 256, 0, stream>>>(boxes, vcnt, mask);
    k3_serial<<<1, 512, 0, stream>>>(mask, zrow, d_srt, vcnt, out);
}